// Round 12
// baseline (500.526 us; speedup 1.0000x reference)
//
#include <hip/hip_runtime.h>

#define B_ 4
#define N_ 16384
#define D_ 64
#define H_ 8
#define E_ 512
#define NCHUNK 16
#define NTILES (N_ / 64)

// ---------------------------------------------------------------------------
// k_init: zero kv_sum (B*H*4096 f32)
// ---------------------------------------------------------------------------
__global__ __launch_bounds__(256) void k_init(float* kv_sum)
{
    kv_sum[blockIdx.x * 256 + threadIdx.x] = 0.f;
}

// ---------------------------------------------------------------------------
// Kernel 1: k,v projection + layernorm + rope(k) + atomic kv accumulation.
// grid (NCHUNK, H, B), 256 threads. Thread tile: 4 rows (r0) x 4 cols (c0).
// ---------------------------------------------------------------------------
__global__ __launch_bounds__(256, 2) void k_kv(
    const float* __restrict__ x,
    const float* __restrict__ pos,
    const float* __restrict__ Wk,
    const float* __restrict__ Wv,
    float* __restrict__ kv_sum)
{
    const int b = blockIdx.z, h = blockIdx.y, chunk = blockIdx.x;
    const int tid = threadIdx.x;

    __shared__ float wsm[2][64 * 68];           // Wk,Wv head slices (f32)
    __shared__ float stage[2][64 * 68];         // ks,vs (xs aliases ks)
    float* xs = stage[0];                       // stride 65 while live
    float* ks = stage[0];                       // stride 68
    float* vs = stage[1];                       // stride 68

    #pragma unroll
    for (int m = 0; m < 2; ++m) {
        const float* W = (m == 0) ? Wk : Wv;
        for (int i = tid; i < 1024; i += 256) {
            int kk = i >> 4, c4 = (i & 15) * 4;
            *(float4*)&wsm[m][kk * 68 + c4] = *(const float4*)&W[(size_t)kk * E_ + h * 64 + c4];
        }
    }

    const int c0 = (tid & 15) * 4;
    const int r0 = (tid >> 4) * 4;
    const float sgn = (c0 < 32) ? -1.0f : 1.0f;   // rotate_half sign
    float invf_[4];
    #pragma unroll
    for (int j = 0; j < 4; ++j)
        invf_[j] = exp2f(-0.4152410118609203f * (float)((c0 + j) & 31)); // 10000^-(e/32)

    float acc_kv[4][4] = {{0.f}};

    __syncthreads();

    for (int tile = chunk; tile < NTILES; tile += NCHUNK) {
        const int n0 = tile * 64;

        // Phase A: x tile -> xs[r*65+kk]
        for (int i = tid; i < 1024; i += 256) {
            int r = i >> 4, c4 = (i & 15) * 4;
            float4 v = *(const float4*)&x[(size_t)(b * N_ + n0 + r) * 64 + c4];
            xs[r * 65 + c4]     = v.x;
            xs[r * 65 + c4 + 1] = v.y;
            xs[r * 65 + c4 + 2] = v.z;
            xs[r * 65 + c4 + 3] = v.w;
        }
        __syncthreads();

        // Phase B: k,v projections into registers
        float ak[4][4] = {{0.f}};
        float av[4][4] = {{0.f}};
        #pragma unroll 4
        for (int kk = 0; kk < 64; ++kk) {
            float a_[4];
            #pragma unroll
            for (int i = 0; i < 4; ++i) a_[i] = xs[(r0 + i) * 65 + kk];
            float4 wk4 = *(const float4*)&wsm[0][kk * 68 + c0];
            float4 wv4 = *(const float4*)&wsm[1][kk * 68 + c0];
            float wk_[4] = {wk4.x, wk4.y, wk4.z, wk4.w};
            float wv_[4] = {wv4.x, wv4.y, wv4.z, wv4.w};
            #pragma unroll
            for (int i = 0; i < 4; ++i)
                #pragma unroll
                for (int j = 0; j < 4; ++j) {
                    ak[i][j] += a_[i] * wk_[j];
                    av[i][j] += a_[i] * wv_[j];
                }
        }

        // LayerNorm k,v: stats across the 16 lanes sharing rows (xor 1,2,4,8)
        float kn[4][4], vn[4][4];
        #pragma unroll
        for (int i = 0; i < 4; ++i) {
            float sk  = ak[i][0] + ak[i][1] + ak[i][2] + ak[i][3];
            float sk2 = ak[i][0]*ak[i][0] + ak[i][1]*ak[i][1] + ak[i][2]*ak[i][2] + ak[i][3]*ak[i][3];
            float sv  = av[i][0] + av[i][1] + av[i][2] + av[i][3];
            float sv2 = av[i][0]*av[i][0] + av[i][1]*av[i][1] + av[i][2]*av[i][2] + av[i][3]*av[i][3];
            #pragma unroll
            for (int msk = 1; msk < 16; msk <<= 1) {
                sk  += __shfl_xor(sk,  msk, 64);
                sk2 += __shfl_xor(sk2, msk, 64);
                sv  += __shfl_xor(sv,  msk, 64);
                sv2 += __shfl_xor(sv2, msk, 64);
            }
            float mk = sk * (1.0f / 64.0f);
            float rk = rsqrtf(sk2 * (1.0f / 64.0f) - mk * mk + 1e-5f);
            float mv = sv * (1.0f / 64.0f);
            float rv = rsqrtf(sv2 * (1.0f / 64.0f) - mv * mv + 1e-5f);
            #pragma unroll
            for (int j = 0; j < 4; ++j) {
                kn[i][j] = (ak[i][j] - mk) * rk;
                vn[i][j] = (av[i][j] - mv) * rv;
            }
        }

        // RoPE(k): half-split pairing; partner col e^32 lives in lane tid^8
        float kr[4][4];
        #pragma unroll
        for (int i = 0; i < 4; ++i) {
            float tpos = pos[(size_t)b * N_ + n0 + r0 + i] * 64.0f;
            #pragma unroll
            for (int j = 0; j < 4; ++j) {
                float ang  = tpos * invf_[j];
                float c    = cosf(ang), s = sinf(ang);
                float part = __shfl_xor(kn[i][j], 8, 64);
                kr[i][j]   = kn[i][j] * c + sgn * part * s;
            }
        }
        __syncthreads();   // xs reads complete before overwrite

        // Phase C: stage k,v to LDS (stride 68)
        #pragma unroll
        for (int i = 0; i < 4; ++i) {
            *(float4*)&ks[(r0 + i) * 68 + c0] = make_float4(kr[i][0], kr[i][1], kr[i][2], kr[i][3]);
            *(float4*)&vs[(r0 + i) * 68 + c0] = make_float4(vn[i][0], vn[i][1], vn[i][2], vn[i][3]);
        }
        __syncthreads();

        // Phase E: kv[d,e] += sum_r k[r,d]*v[r,e]
        #pragma unroll 4
        for (int r = 0; r < 64; ++r) {
            float4 ka = *(const float4*)&ks[r * 68 + r0];
            float4 vb = *(const float4*)&vs[r * 68 + c0];
            float ka_[4] = {ka.x, ka.y, ka.z, ka.w};
            float vb_[4] = {vb.x, vb.y, vb.z, vb.w};
            #pragma unroll
            for (int i = 0; i < 4; ++i)
                #pragma unroll
                for (int j = 0; j < 4; ++j)
                    acc_kv[i][j] += ka_[i] * vb_[j];
        }
        __syncthreads();
    }

    float* dst = kv_sum + (size_t)(b * H_ + h) * 4096;
    #pragma unroll
    for (int i = 0; i < 4; ++i)
        #pragma unroll
        for (int j = 0; j < 4; ++j)
            atomicAdd(&dst[(size_t)(r0 + i) * 64 + c0 + j], acc_kv[i][j]);
}

// ---------------------------------------------------------------------------
// Kernel 2: M[b, h*64+d, j] = (1/N) * sum_e kv[b,h,d,e] * Wo[h*64+e, j]
// ---------------------------------------------------------------------------
__global__ __launch_bounds__(256) void k_m(
    const float* __restrict__ kv_sum,
    const float* __restrict__ Wo,
    float* __restrict__ M)
{
    const int h = blockIdx.x, b = blockIdx.y;
    const int tid = threadIdx.x;
    __shared__ float kvs[64 * 65];
    __shared__ float wos[64 * 68];

    for (int i = tid; i < 4096; i += 256) {
        int d = i >> 6, e = i & 63;
        kvs[d * 65 + e] = kv_sum[(size_t)(b * H_ + h) * 4096 + i];
    }
    for (int i = tid; i < 1024; i += 256) {
        int dp = i >> 4, j4 = (i & 15) * 4;
        *(float4*)&wos[dp * 68 + j4] = *(const float4*)&Wo[(size_t)(h * 64 + dp) * 64 + j4];
    }
    __syncthreads();

    const int j0 = (tid & 15) * 4, d0 = (tid >> 4) * 4;
    float acc[4][4] = {{0.f}};
    #pragma unroll 4
    for (int dp = 0; dp < 64; ++dp) {
        float a_[4];
        #pragma unroll
        for (int i = 0; i < 4; ++i) a_[i] = kvs[(d0 + i) * 65 + dp];
        float4 w4 = *(const float4*)&wos[dp * 68 + j0];
        float w_[4] = {w4.x, w4.y, w4.z, w4.w};
        #pragma unroll
        for (int i = 0; i < 4; ++i)
            #pragma unroll
            for (int j = 0; j < 4; ++j)
                acc[i][j] += a_[i] * w_[j];
    }
    const float inv_n = 1.0f / (float)N_;
    #pragma unroll
    for (int i = 0; i < 4; ++i)
        *(float4*)&M[((size_t)b * E_ + h * 64 + d0 + i) * 64 + j0] =
            make_float4(acc[i][0] * inv_n, acc[i][1] * inv_n,
                        acc[i][2] * inv_n, acc[i][3] * inv_n);
}

// ---------------------------------------------------------------------------
// Kernel 3: out[b,n,:] = sum_h rope(x@Wq_h) @ M[b,h]   grid (N/64, B)
// OUTPUT IS FLOAT32 (fix from R11 oracle: buffer is 4 B/elem).
// ---------------------------------------------------------------------------
__global__ __launch_bounds__(256, 2) void k_out(
    const float* __restrict__ x,
    const float* __restrict__ pos,
    const float* __restrict__ Wq,
    const float* __restrict__ M,
    float* __restrict__ out)
{
    const int b = blockIdx.y;
    const int n0 = blockIdx.x * 64;
    const int tid = threadIdx.x;
    __shared__ float xs[64 * 65];               // stride 65
    __shared__ float Ms[64 * 68];               // stride 68
    __shared__ float qst[64 * 65];              // stride 65
    __shared__ float wq_s[64 * 68];             // stride 68

    const int c0 = (tid & 15) * 4, r0 = (tid >> 4) * 4;
    const float sgn = (c0 < 32) ? -1.f : 1.f;

    for (int i = tid; i < 1024; i += 256) {
        int r = i >> 4, c4 = (i & 15) * 4;
        float4 v = *(const float4*)&x[(size_t)(b * N_ + n0 + r) * 64 + c4];
        xs[r * 65 + c4]     = v.x;
        xs[r * 65 + c4 + 1] = v.y;
        xs[r * 65 + c4 + 2] = v.z;
        xs[r * 65 + c4 + 3] = v.w;
    }
    float invf_[4];
    #pragma unroll
    for (int j = 0; j < 4; ++j)
        invf_[j] = exp2f(-0.4152410118609203f * (float)((c0 + j) & 31));
    float cs[4][4], sn[4][4];
    #pragma unroll
    for (int i = 0; i < 4; ++i) {
        float tpos = pos[(size_t)b * N_ + n0 + r0 + i] * 64.0f;
        #pragma unroll
        for (int j = 0; j < 4; ++j) {
            float ang = tpos * invf_[j];
            cs[i][j] = cosf(ang);
            sn[i][j] = sinf(ang);
        }
    }

    float oacc[4][4] = {{0.f}};
    for (int h = 0; h < H_; ++h) {
        for (int i = tid; i < 1024; i += 256) {
            int kk = i >> 4, c4 = (i & 15) * 4;
            *(float4*)&wq_s[kk * 68 + c4] = *(const float4*)&Wq[(size_t)kk * E_ + h * 64 + c4];
        }
        for (int i = tid; i < 1024; i += 256) {
            int er = i >> 4, j4 = (i & 15) * 4;
            *(float4*)&Ms[er * 68 + j4] = *(const float4*)&M[((size_t)b * E_ + h * 64 + er) * 64 + j4];
        }
        __syncthreads();

        float aq[4][4] = {{0.f}};
        #pragma unroll 4
        for (int kk = 0; kk < 64; ++kk) {
            float a_[4];
            #pragma unroll
            for (int i = 0; i < 4; ++i) a_[i] = xs[(r0 + i) * 65 + kk];
            float4 w4 = *(const float4*)&wq_s[kk * 68 + c0];
            float w_[4] = {w4.x, w4.y, w4.z, w4.w};
            #pragma unroll
            for (int i = 0; i < 4; ++i)
                #pragma unroll
                for (int j = 0; j < 4; ++j)
                    aq[i][j] += a_[i] * w_[j];
        }

        // RoPE(q), half-split; partner via lane^8
        #pragma unroll
        for (int i = 0; i < 4; ++i) {
            #pragma unroll
            for (int j = 0; j < 4; ++j) {
                float part = __shfl_xor(aq[i][j], 8, 64);
                qst[(r0 + i) * 65 + c0 + j] = aq[i][j] * cs[i][j] + sgn * part * sn[i][j];
            }
        }
        __syncthreads();

        #pragma unroll 4
        for (int kk = 0; kk < 64; ++kk) {
            float a_[4];
            #pragma unroll
            for (int i = 0; i < 4; ++i) a_[i] = qst[(r0 + i) * 65 + kk];
            float4 m4 = *(const float4*)&Ms[kk * 68 + c0];
            float m_[4] = {m4.x, m4.y, m4.z, m4.w};
            #pragma unroll
            for (int i = 0; i < 4; ++i)
                #pragma unroll
                for (int j = 0; j < 4; ++j)
                    oacc[i][j] += a_[i] * m_[j];
        }
        __syncthreads();
    }

    #pragma unroll
    for (int i = 0; i < 4; ++i)
        *(float4*)&out[(size_t)(b * N_ + n0 + r0 + i) * 64 + c0] =
            make_float4(oacc[i][0], oacc[i][1], oacc[i][2], oacc[i][3]);
}

// ---------------------------------------------------------------------------
extern "C" void kernel_launch(void* const* d_in, const int* in_sizes, int n_in,
                              void* d_out, int out_size, void* d_ws, size_t ws_size,
                              hipStream_t stream)
{
    const float* x   = (const float*)d_in[0];
    const float* pos = (const float*)d_in[1];
    const float* Wq  = (const float*)d_in[2];
    const float* Wk  = (const float*)d_in[3];
    const float* Wv  = (const float*)d_in[4];
    const float* Wo  = (const float*)d_in[5];
    float* out = (float*)d_out;                 // f32 output (R11 oracle)

    char* ws = (char*)d_ws;
    float* kv_sum = (float*)ws;                 // 512 KB
    float* M      = (float*)(ws + 524288);      // 512 KB

    k_init<<<dim3(512), 256, 0, stream>>>(kv_sum);
    k_kv  <<<dim3(NCHUNK, H_, B_), 256, 0, stream>>>(x, pos, Wk, Wv, kv_sum);
    k_m   <<<dim3(H_, B_), 256, 0, stream>>>(kv_sum, Wo, M);
    k_out <<<dim3(NTILES, B_), 256, 0, stream>>>(x, pos, Wq, M, out);
}

// Round 13
// 266.735 us; speedup vs baseline: 1.8765x; 1.8765x over previous
//
#include <hip/hip_runtime.h>

#define B_ 4
#define N_ 16384
#define D_ 64
#define H_ 8
#define E_ 512
#define NCHUNK 24
#define NTILES (N_ / 64)

typedef __attribute__((ext_vector_type(8))) short short8;
typedef __attribute__((ext_vector_type(4))) float f32x4;

// f32 -> bf16 (RNE)
__device__ __forceinline__ unsigned short f2b(float f) {
    unsigned u = __float_as_uint(f);
    return (unsigned short)((u + 0x7fffu + ((u >> 16) & 1u)) >> 16);
}

// ---------------------------------------------------------------------------
// k_init: zero kv_sum (B*H*4096 f32)
// ---------------------------------------------------------------------------
__global__ __launch_bounds__(256) void k_init(float* kv_sum)
{
    kv_sum[blockIdx.x * 256 + threadIdx.x] = 0.f;
}

// ---------------------------------------------------------------------------
// Kernel 1 (MFMA): k,v projection + LN + RoPE(k) + kv accumulation.
// grid (NCHUNK, H, B), 256 thr = 4 waves. mfma_f32_16x16x32_bf16.
// Layouts (verified): A[m=lane&15][k=quad*8+j]; D col=lane&15,row=quad*4+reg.
// LDS rows stride 72 u16 = 144 B (16B-aligned for b128 frag loads).
// ---------------------------------------------------------------------------
__global__ __launch_bounds__(256, 3) void k_kv(
    const float* __restrict__ x,
    const float* __restrict__ pos,
    const float* __restrict__ Wk,
    const float* __restrict__ Wv,
    float* __restrict__ kv_sum)
{
    const int b = blockIdx.z, h = blockIdx.y, chunk = blockIdx.x;
    const int tid  = threadIdx.x;
    const int lane = tid & 63;
    const int w    = tid >> 6;        // wave id 0..3
    const int c    = lane & 15;
    const int quad = lane >> 4;
    const int m0   = w * 16;          // wave's 16-row band (tokens in proj, feats in kv)

    __shared__ unsigned short xbuf[64 * 72];   // x tile bf16 [tok][kin]
    __shared__ unsigned short wkb[64 * 72];    // Wk^T bf16 [feat][kin]
    __shared__ unsigned short wvb[64 * 72];    // Wv^T bf16 [feat][kin]
    __shared__ unsigned short kbuf[64 * 72];   // k bf16 [feat][tok]
    __shared__ unsigned short vbuf[64 * 72];   // v bf16 [feat][tok]
    __shared__ float posb[64];

    // Stage W transposed (once per block, amortized over ~11 tiles)
    for (int i = tid; i < 1024; i += 256) {
        int kin = i >> 4, c4 = (i & 15) * 4;
        float4 wk4 = *(const float4*)&Wk[(size_t)kin * E_ + h * 64 + c4];
        float4 wv4 = *(const float4*)&Wv[(size_t)kin * E_ + h * 64 + c4];
        wkb[(c4 + 0) * 72 + kin] = f2b(wk4.x);
        wkb[(c4 + 1) * 72 + kin] = f2b(wk4.y);
        wkb[(c4 + 2) * 72 + kin] = f2b(wk4.z);
        wkb[(c4 + 3) * 72 + kin] = f2b(wk4.w);
        wvb[(c4 + 0) * 72 + kin] = f2b(wv4.x);
        wvb[(c4 + 1) * 72 + kin] = f2b(wv4.y);
        wvb[(c4 + 2) * 72 + kin] = f2b(wv4.z);
        wvb[(c4 + 3) * 72 + kin] = f2b(wv4.w);
    }

    const float invf_lo = exp2f(-0.4152410118609203f * (float)c);  // 10000^(-c/32)
    const float invf_hi = invf_lo * 0.01f;                          // 10000^(-(16+c)/32)

    f32x4 akv[4];
    #pragma unroll
    for (int nt = 0; nt < 4; ++nt) akv[nt] = (f32x4){0.f, 0.f, 0.f, 0.f};

    for (int tile = chunk; tile < NTILES; tile += NCHUNK) {
        const int n0 = tile * 64;

        // ---- stage x tile (bf16) + pos ----
        for (int i = tid; i < 1024; i += 256) {
            int r = i >> 4, c4 = (i & 15) * 4;
            float4 v = *(const float4*)&x[(size_t)(b * N_ + n0 + r) * 64 + c4];
            ushort4 u;
            u.x = f2b(v.x); u.y = f2b(v.y); u.z = f2b(v.z); u.w = f2b(v.w);
            *(ushort4*)&xbuf[r * 72 + c4] = u;
        }
        if (tid < 64) posb[tid] = pos[(size_t)b * N_ + n0 + tid] * 64.0f;
        __syncthreads();

        // ---- proj: tokens m0..m0+15 x feats 0..63, K=64 (2 steps) ----
        short8 a0 = *(const short8*)&xbuf[(m0 + c) * 72 + quad * 8];
        short8 a1 = *(const short8*)&xbuf[(m0 + c) * 72 + 32 + quad * 8];
        f32x4 ak[4], av[4];
        #pragma unroll
        for (int nt = 0; nt < 4; ++nt) {
            short8 bk0 = *(const short8*)&wkb[(nt * 16 + c) * 72 + quad * 8];
            short8 bk1 = *(const short8*)&wkb[(nt * 16 + c) * 72 + 32 + quad * 8];
            f32x4 z = {0.f, 0.f, 0.f, 0.f};
            z = __builtin_amdgcn_mfma_f32_16x16x32_bf16(a0, bk0, z, 0, 0, 0);
            ak[nt] = __builtin_amdgcn_mfma_f32_16x16x32_bf16(a1, bk1, z, 0, 0, 0);
            short8 bv0 = *(const short8*)&wvb[(nt * 16 + c) * 72 + quad * 8];
            short8 bv1 = *(const short8*)&wvb[(nt * 16 + c) * 72 + 32 + quad * 8];
            f32x4 y = {0.f, 0.f, 0.f, 0.f};
            y = __builtin_amdgcn_mfma_f32_16x16x32_bf16(a0, bv0, y, 0, 0, 0);
            av[nt] = __builtin_amdgcn_mfma_f32_16x16x32_bf16(a1, bv1, y, 0, 0, 0);
        }

        // ---- LN per token (row = quad*4+r; feats spread over nt x 16 lanes) ----
        float kn[4][4], vn[4][4];   // [nt][r]
        #pragma unroll
        for (int r = 0; r < 4; ++r) {
            float sk  = ak[0][r] + ak[1][r] + ak[2][r] + ak[3][r];
            float sk2 = ak[0][r]*ak[0][r] + ak[1][r]*ak[1][r] + ak[2][r]*ak[2][r] + ak[3][r]*ak[3][r];
            float sv  = av[0][r] + av[1][r] + av[2][r] + av[3][r];
            float sv2 = av[0][r]*av[0][r] + av[1][r]*av[1][r] + av[2][r]*av[2][r] + av[3][r]*av[3][r];
            #pragma unroll
            for (int msk = 1; msk < 16; msk <<= 1) {
                sk  += __shfl_xor(sk,  msk, 64);
                sk2 += __shfl_xor(sk2, msk, 64);
                sv  += __shfl_xor(sv,  msk, 64);
                sv2 += __shfl_xor(sv2, msk, 64);
            }
            float mk = sk * (1.0f / 64.0f);
            float rk = rsqrtf(sk2 * (1.0f / 64.0f) - mk * mk + 1e-5f);
            float mv = sv * (1.0f / 64.0f);
            float rv = rsqrtf(sv2 * (1.0f / 64.0f) - mv * mv + 1e-5f);
            #pragma unroll
            for (int nt = 0; nt < 4; ++nt) {
                kn[nt][r] = (ak[nt][r] - mk) * rk;
                vn[nt][r] = (av[nt][r] - mv) * rv;
            }
        }

        // ---- RoPE(k): feat=16nt+c; partner feat^32 = tile nt^2, same lane ----
        #pragma unroll
        for (int r = 0; r < 4; ++r) {
            float tp = posb[m0 + quad * 4 + r];
            float al = tp * invf_lo, ah = tp * invf_hi;
            float cl = __cosf(al), sl = __sinf(al);
            float ch = __cosf(ah), sh = __sinf(ah);
            float lo0 = kn[0][r], hi0 = kn[2][r];
            kn[0][r] = lo0 * cl - hi0 * sl;
            kn[2][r] = hi0 * cl + lo0 * sl;
            float lo1 = kn[1][r], hi1 = kn[3][r];
            kn[1][r] = lo1 * ch - hi1 * sh;
            kn[3][r] = hi1 * ch + lo1 * sh;
        }

        // ---- pack bf16, store transposed [feat][tok] ----
        #pragma unroll
        for (int nt = 0; nt < 4; ++nt) {
            ushort4 pk, pv;
            pk.x = f2b(kn[nt][0]); pk.y = f2b(kn[nt][1]); pk.z = f2b(kn[nt][2]); pk.w = f2b(kn[nt][3]);
            pv.x = f2b(vn[nt][0]); pv.y = f2b(vn[nt][1]); pv.z = f2b(vn[nt][2]); pv.w = f2b(vn[nt][3]);
            *(ushort4*)&kbuf[(nt * 16 + c) * 72 + m0 + quad * 4] = pk;
            *(ushort4*)&vbuf[(nt * 16 + c) * 72 + m0 + quad * 4] = pv;
        }
        __syncthreads();

        // ---- kv += k^T v : wave's d-band = 16w..16w+15, K = 64 toks ----
        short8 ka0 = *(const short8*)&kbuf[(m0 + c) * 72 + quad * 8];
        short8 ka1 = *(const short8*)&kbuf[(m0 + c) * 72 + 32 + quad * 8];
        #pragma unroll
        for (int nt = 0; nt < 4; ++nt) {
            short8 vb0 = *(const short8*)&vbuf[(nt * 16 + c) * 72 + quad * 8];
            short8 vb1 = *(const short8*)&vbuf[(nt * 16 + c) * 72 + 32 + quad * 8];
            akv[nt] = __builtin_amdgcn_mfma_f32_16x16x32_bf16(ka0, vb0, akv[nt], 0, 0, 0);
            akv[nt] = __builtin_amdgcn_mfma_f32_16x16x32_bf16(ka1, vb1, akv[nt], 0, 0, 0);
        }
        // next-iter loop-top __syncthreads orders kv reads vs. next writes
    }

    // kv D-layout: d = 16w + quad*4 + r, e = 16nt + c
    float* dst = kv_sum + (size_t)(b * H_ + h) * 4096;
    #pragma unroll
    for (int nt = 0; nt < 4; ++nt)
        #pragma unroll
        for (int r = 0; r < 4; ++r)
            atomicAdd(&dst[(size_t)(16 * w + quad * 4 + r) * 64 + nt * 16 + c], akv[nt][r]);
}

// ---------------------------------------------------------------------------
// Kernel 2: M[b, h*64+d, j] = (1/N) * sum_e kv[b,h,d,e] * Wo[h*64+e, j]
// ---------------------------------------------------------------------------
__global__ __launch_bounds__(256) void k_m(
    const float* __restrict__ kv_sum,
    const float* __restrict__ Wo,
    float* __restrict__ M)
{
    const int h = blockIdx.x, b = blockIdx.y;
    const int tid = threadIdx.x;
    __shared__ float kvs[64 * 65];
    __shared__ float wos[64 * 68];

    for (int i = tid; i < 4096; i += 256) {
        int d = i >> 6, e = i & 63;
        kvs[d * 65 + e] = kv_sum[(size_t)(b * H_ + h) * 4096 + i];
    }
    for (int i = tid; i < 1024; i += 256) {
        int dp = i >> 4, j4 = (i & 15) * 4;
        *(float4*)&wos[dp * 68 + j4] = *(const float4*)&Wo[(size_t)(h * 64 + dp) * 64 + j4];
    }
    __syncthreads();

    const int j0 = (tid & 15) * 4, d0 = (tid >> 4) * 4;
    float acc[4][4] = {{0.f}};
    #pragma unroll 4
    for (int dp = 0; dp < 64; ++dp) {
        float a_[4];
        #pragma unroll
        for (int i = 0; i < 4; ++i) a_[i] = kvs[(d0 + i) * 65 + dp];
        float4 w4 = *(const float4*)&wos[dp * 68 + j0];
        float w_[4] = {w4.x, w4.y, w4.z, w4.w};
        #pragma unroll
        for (int i = 0; i < 4; ++i)
            #pragma unroll
            for (int j = 0; j < 4; ++j)
                acc[i][j] += a_[i] * w_[j];
    }
    const float inv_n = 1.0f / (float)N_;
    #pragma unroll
    for (int i = 0; i < 4; ++i)
        *(float4*)&M[((size_t)b * E_ + h * 64 + d0 + i) * 64 + j0] =
            make_float4(acc[i][0] * inv_n, acc[i][1] * inv_n,
                        acc[i][2] * inv_n, acc[i][3] * inv_n);
}

// ---------------------------------------------------------------------------
// Kernel 3: out[b,n,:] = sum_h rope(x@Wq_h) @ M[b,h]   grid (N/64, B). f32 out.
// (unchanged from R12 except native trig)
// ---------------------------------------------------------------------------
__global__ __launch_bounds__(256, 2) void k_out(
    const float* __restrict__ x,
    const float* __restrict__ pos,
    const float* __restrict__ Wq,
    const float* __restrict__ M,
    float* __restrict__ out)
{
    const int b = blockIdx.y;
    const int n0 = blockIdx.x * 64;
    const int tid = threadIdx.x;
    __shared__ float xs[64 * 65];
    __shared__ float Ms[64 * 68];
    __shared__ float qst[64 * 65];
    __shared__ float wq_s[64 * 68];

    const int c0 = (tid & 15) * 4, r0 = (tid >> 4) * 4;
    const float sgn = (c0 < 32) ? -1.f : 1.f;

    for (int i = tid; i < 1024; i += 256) {
        int r = i >> 4, c4 = (i & 15) * 4;
        float4 v = *(const float4*)&x[(size_t)(b * N_ + n0 + r) * 64 + c4];
        xs[r * 65 + c4]     = v.x;
        xs[r * 65 + c4 + 1] = v.y;
        xs[r * 65 + c4 + 2] = v.z;
        xs[r * 65 + c4 + 3] = v.w;
    }
    float invf_[4];
    #pragma unroll
    for (int j = 0; j < 4; ++j)
        invf_[j] = exp2f(-0.4152410118609203f * (float)((c0 + j) & 31));
    float cs[4][4], sn[4][4];
    #pragma unroll
    for (int i = 0; i < 4; ++i) {
        float tpos = pos[(size_t)b * N_ + n0 + r0 + i] * 64.0f;
        #pragma unroll
        for (int j = 0; j < 4; ++j) {
            float ang = tpos * invf_[j];
            cs[i][j] = __cosf(ang);
            sn[i][j] = __sinf(ang);
        }
    }

    float oacc[4][4] = {{0.f}};
    for (int h = 0; h < H_; ++h) {
        for (int i = tid; i < 1024; i += 256) {
            int kk = i >> 4, c4 = (i & 15) * 4;
            *(float4*)&wq_s[kk * 68 + c4] = *(const float4*)&Wq[(size_t)kk * E_ + h * 64 + c4];
        }
        for (int i = tid; i < 1024; i += 256) {
            int er = i >> 4, j4 = (i & 15) * 4;
            *(float4*)&Ms[er * 68 + j4] = *(const float4*)&M[((size_t)b * E_ + h * 64 + er) * 64 + j4];
        }
        __syncthreads();

        float aq[4][4] = {{0.f}};
        #pragma unroll 4
        for (int kk = 0; kk < 64; ++kk) {
            float a_[4];
            #pragma unroll
            for (int i = 0; i < 4; ++i) a_[i] = xs[(r0 + i) * 65 + kk];
            float4 w4 = *(const float4*)&wq_s[kk * 68 + c0];
            float w_[4] = {w4.x, w4.y, w4.z, w4.w};
            #pragma unroll
            for (int i = 0; i < 4; ++i)
                #pragma unroll
                for (int j = 0; j < 4; ++j)
                    aq[i][j] += a_[i] * w_[j];
        }

        #pragma unroll
        for (int i = 0; i < 4; ++i) {
            #pragma unroll
            for (int j = 0; j < 4; ++j) {
                float part = __shfl_xor(aq[i][j], 8, 64);
                qst[(r0 + i) * 65 + c0 + j] = aq[i][j] * cs[i][j] + sgn * part * sn[i][j];
            }
        }
        __syncthreads();

        #pragma unroll 4
        for (int kk = 0; kk < 64; ++kk) {
            float a_[4];
            #pragma unroll
            for (int i = 0; i < 4; ++i) a_[i] = qst[(r0 + i) * 65 + kk];
            float4 m4 = *(const float4*)&Ms[kk * 68 + c0];
            float m_[4] = {m4.x, m4.y, m4.z, m4.w};
            #pragma unroll
            for (int i = 0; i < 4; ++i)
                #pragma unroll
                for (int j = 0; j < 4; ++j)
                    oacc[i][j] += a_[i] * m_[j];
        }
        __syncthreads();
    }

    #pragma unroll
    for (int i = 0; i < 4; ++i)
        *(float4*)&out[(size_t)(b * N_ + n0 + r0 + i) * 64 + c0] =
            make_float4(oacc[i][0], oacc[i][1], oacc[i][2], oacc[i][3]);
}

// ---------------------------------------------------------------------------
extern "C" void kernel_launch(void* const* d_in, const int* in_sizes, int n_in,
                              void* d_out, int out_size, void* d_ws, size_t ws_size,
                              hipStream_t stream)
{
    const float* x   = (const float*)d_in[0];
    const float* pos = (const float*)d_in[1];
    const float* Wq  = (const float*)d_in[2];
    const float* Wk  = (const float*)d_in[3];
    const float* Wv  = (const float*)d_in[4];
    const float* Wo  = (const float*)d_in[5];
    float* out = (float*)d_out;

    char* ws = (char*)d_ws;
    float* kv_sum = (float*)ws;                 // 512 KB
    float* M      = (float*)(ws + 524288);      // 512 KB

    k_init<<<dim3(512), 256, 0, stream>>>(kv_sum);
    k_kv  <<<dim3(NCHUNK, H_, B_), 256, 0, stream>>>(x, pos, Wk, Wv, kv_sum);
    k_m   <<<dim3(H_, B_), 256, 0, stream>>>(kv_sum, Wo, M);
    k_out <<<dim3(NTILES, B_), 256, 0, stream>>>(x, pos, Wq, M, out);
}